// Round 10
// baseline (157.688 us; speedup 1.0000x reference)
//
#include <hip/hip_runtime.h>
#include <hip/hip_bf16.h>

// Problem constants
#define NB   8
#define CCH  64
#define CR8  8
#define NPX  2304           // 48*48
#define BCN  (NB*CCH*NPX)   // 1179648
#define LOG2E 1.4426950408889634f

typedef short  short8   __attribute__((ext_vector_type(8)));
typedef unsigned short ushort8t __attribute__((ext_vector_type(8)));
typedef float  float4t  __attribute__((ext_vector_type(4)));
typedef float  float16t __attribute__((ext_vector_type(16)));

// round-half-up bf16 from f32: (u + 0x8000) >> 16  (<=1 ulp vs RNE)
static __device__ __forceinline__ unsigned short bf16r(float f) {
    return (unsigned short)((__float_as_uint(f) + 0x8000u) >> 16);
}
// pack two f32 -> two bf16 in one dword: [hi16(hi) : hi16(lo)], 3 VALU inst
static __device__ __forceinline__ unsigned int pack_bf16(float lo, float hi) {
    const unsigned int ul = __float_as_uint(lo) + 0x8000u;
    const unsigned int uh = __float_as_uint(hi) + 0x8000u;
    return __builtin_amdgcn_perm(uh, ul, 0x07060302u);
}
// 8 floats -> short8 bf16 fragment (4 perms)
static __device__ __forceinline__ short8 pack8(const float* f) {
    union { unsigned int u[4]; short8 s; } r;
    #pragma unroll
    for (int j = 0; j < 4; j++) r.u[j] = pack_bf16(f[2*j], f[2*j+1]);
    return r.s;
}

// Workspace layout (float offsets)
// qb/kb: bf16 [b][i][16] rows. qb: c 0..7 = q*log2e, slots 8/9 get
// -log2(D_i) hi/lo AFTER stats (merge_fold); kb: c 0..7 = k, slots 8/9 = 1.0.
// The S-MFMA in out_kernel then yields log2(P_normalized) directly.
#define WS_QB1 0
#define WS_KB1 (WS_QB1 + 147456)
#define WS_QB2 (WS_KB1 + 147456)
#define WS_KB2 (WS_QB2 + 147456)
#define WS_V1  (WS_KB2 + 147456)        // bf16 [b][c][i], unscaled
#define WS_V2  (WS_V1 + BCN/2)
#define WS_PD  (WS_V2 + BCN/2)          // partial denom [a][b][jsb=18][i] fp32

// ---------------------------------------------------------------------------
// Kernel 1: projections as MFMA GEMM. M=160 rows (qk1,qk2,v1,v2), N=px, K=64.
// grid (72 pxtiles of 32, 8 b), block 256 = 4 independent waves, NO LDS,
// NO barriers. Also writes out = x residual-init. kb pad slots 8,9 = 1.0.
// ---------------------------------------------------------------------------
__global__ __launch_bounds__(256) void proj_kernel(
    const float* __restrict__ x1, const float* __restrict__ x2,
    const float* __restrict__ Wqk1, const float* __restrict__ bqk1,
    const float* __restrict__ Wqk2, const float* __restrict__ bqk2,
    const float* __restrict__ Wv1,  const float* __restrict__ bv1,
    const float* __restrict__ Wv2,  const float* __restrict__ bv2,
    float* __restrict__ ws, float* __restrict__ out)
{
    const int t    = threadIdx.x;
    const int lane = t & 63;
    const int w    = t >> 6;
    const int n16  = lane & 15;
    const int c4   = lane >> 4;
    const int nt   = w & 1;
    const int mh   = w >> 1;
    const int b    = blockIdx.y;
    const int px   = blockIdx.x * 32 + nt * 16 + n16;

    const float* xsb[2];
    xsb[0] = x1 + ((size_t)b * CCH) * NPX + px;
    xsb[1] = x2 + ((size_t)b * CCH) * NPX + px;

    float xr[2][16];
    short8 bfrag[2][2];
    #pragma unroll
    for (int st = 0; st < 2; st++) {
        #pragma unroll
        for (int ch = 0; ch < 2; ch++) {
            #pragma unroll
            for (int j = 0; j < 8; j++)
                xr[st][ch * 8 + j] = xsb[st][(ch * 32 + c4 * 8 + j) * NPX];
            bfrag[st][ch] = pack8(&xr[st][ch * 8]);
        }
    }

    if (mh == 0) {
        #pragma unroll
        for (int st = 0; st < 2; st++) {
            float* outs = out + (st ? (size_t)BCN : 0);
            #pragma unroll
            for (int e = 0; e < 16; e++) {
                const int ch = (e >> 3) * 32 + c4 * 8 + (e & 7);
                outs[((size_t)b * CCH + ch) * NPX + px] = xr[st][e];
            }
        }
    }

    float4t acc[5];
    #pragma unroll
    for (int mt = 0; mt < 5; mt++) { acc[mt][0]=0.f; acc[mt][1]=0.f; acc[mt][2]=0.f; acc[mt][3]=0.f; }

    #pragma unroll
    for (int mt = 0; mt < 5; mt++) {
        const int mi  = mh * 5 + mt;
        const int isqk = (mi < 2);
        const int st  = isqk ? (mi & 1) : (mi >= 6);
        const float* Wb;
        int rowbase;
        if (isqk) { Wb = (mi == 0) ? Wqk1 : Wqk2; rowbase = 0; }
        else      { Wb = (mi >= 6) ? Wv2 : Wv1; rowbase = (mi - (mi >= 6 ? 6 : 2)) * 16; }
        const float* wrow = Wb + (size_t)(rowbase + n16) * 64 + c4 * 8;

        const short8 bf0 = st ? bfrag[1][0] : bfrag[0][0];
        const short8 bf1 = st ? bfrag[1][1] : bfrag[0][1];

        #pragma unroll
        for (int ch = 0; ch < 2; ch++) {
            float fa[8];
            const float4 a0 = *(const float4*)(wrow + ch * 32);
            const float4 a1 = *(const float4*)(wrow + ch * 32 + 4);
            fa[0] = a0.x; fa[1] = a0.y; fa[2] = a0.z; fa[3] = a0.w;
            fa[4] = a1.x; fa[5] = a1.y; fa[6] = a1.z; fa[7] = a1.w;
            acc[mt] = __builtin_amdgcn_mfma_f32_16x16x32_bf16(
                pack8(fa), ch ? bf1 : bf0, acc[mt], 0, 0, 0);
        }
    }

    #pragma unroll
    for (int mt = 0; mt < 5; mt++) {
        const int mi = mh * 5 + mt;
        if (mi < 2) {                       // qk tile (wave-uniform branch)
            const int st = mi & 1;
            const float* bqk = st ? bqk2 : bqk1;
            unsigned short* qb = (unsigned short*)(ws + (st ? WS_QB2 : WS_QB1));
            unsigned short* kb = (unsigned short*)(ws + (st ? WS_KB2 : WS_KB1));
            const size_t rbase = (size_t)(b * NPX + px) * 16;
            #pragma unroll
            for (int r = 0; r < 4; r++) {
                const int oc = c4 * 4 + r;
                const float val = acc[mt][r] + bqk[oc];
                if (oc < 8)
                    qb[rbase + oc] = bf16r(val * LOG2E);
                else
                    kb[rbase + (oc - 8)] = bf16r(val);
            }
            ushort8t zq, zk;
            #pragma unroll
            for (int e = 0; e < 8; e++) { zq[e] = 0; zk[e] = 0; }
            zk[0] = 0x3F80; zk[1] = 0x3F80;   // kb slots 8,9 = bf16(1.0)
            if (c4 == 0) *(ushort8t*)(qb + rbase + 8) = zq;
            if (c4 == 2) *(ushort8t*)(kb + rbase + 8) = zk;
        } else {                            // v tile
            const int st = (mi >= 6);
            const int vt_ = mi - (st ? 6 : 2);
            const float* bv = st ? bv2 : bv1;
            unsigned short* v = (unsigned short*)(ws + (st ? WS_V2 : WS_V1));
            #pragma unroll
            for (int r = 0; r < 4; r++) {
                const int oc = vt_ * 16 + c4 * 4 + r;
                const float val = acc[mt][r] + bv[oc];
                v[((size_t)b * CCH + oc) * NPX + px] = bf16r(val);
            }
        }
    }
}

// ---------------------------------------------------------------------------
// Kernel 2: softmax denominators via MFMA, barrier-free inner loop with
// 1-deep qfrag prefetch, pointer-incremented addressing.
// grid (18 jsb, 4 iq, 16 ab), block 256.
// ---------------------------------------------------------------------------
__global__ __launch_bounds__(256) void stats_kernel(float* __restrict__ ws)
{
    const int t  = threadIdx.x;
    const int w  = t >> 6;
    const int n  = t & 31;
    const int h  = (t & 63) >> 5;
    const int jsb = blockIdx.x;     // 0..17
    const int iq  = blockIdx.y;     // 0..3
    const int ab  = blockIdx.z;     // a*8+b
    const int b   = ab & 7;
    const int a   = ab >> 3;

    const unsigned short* qb = (const unsigned short*)(ws + (a ? WS_QB2 : WS_QB1));
    const unsigned short* kb = (const unsigned short*)(ws + (a ? WS_KB2 : WS_KB1));
    float* pd = ws + WS_PD;

    __shared__ float red[4][576];

    const int j = jsb * 128 + w * 32 + n;
    const short8 kfrag = *(const short8*)(kb + (size_t)(b * NPX + j) * 16 + h * 8);

    const unsigned short* qp = qb + (size_t)(b * NPX + iq * 576 + n) * 16 + h * 8;
    short8 qf = *(const short8*)qp;

    for (int ib = 0; ib < 18; ib++) {
        qp += 512;                  // next 32-row i-block
        short8 qn = qf;
        if (ib + 1 < 18) qn = *(const short8*)qp;
        float16t acc = {};
        acc = __builtin_amdgcn_mfma_f32_32x32x16_bf16(kfrag, qf, acc, 0, 0, 0);
        float s0 = 0.f, s1 = 0.f, s2 = 0.f, s3 = 0.f;
        #pragma unroll
        for (int r = 0; r < 4; r++) {
            s0 += exp2f(acc[4 * r + 0]);
            s1 += exp2f(acc[4 * r + 1]);
            s2 += exp2f(acc[4 * r + 2]);
            s3 += exp2f(acc[4 * r + 3]);
        }
        float ssum = (s0 + s1) + (s2 + s3);
        ssum += __shfl_xor(ssum, 32);
        if (h == 0) red[w][ib * 32 + n] = ssum;
        qf = qn;
    }
    __syncthreads();
    for (int idx = t; idx < 576; idx += 256)
        pd[((size_t)ab * 18 + jsb) * NPX + iq * 576 + idx] =
            red[0][idx] + red[1][idx] + red[2][idx] + red[3][idx];
}

// ---------------------------------------------------------------------------
// Kernel 3: merge 18 partials -> m = -log2(D_i), folded into qb slots 8/9
// (hi/lo bf16 split, error ~2^-17). grid (144), block 256. Tiny.
// ---------------------------------------------------------------------------
__global__ __launch_bounds__(256) void merge_fold(float* __restrict__ ws)
{
    const float* pd = ws + WS_PD;
    const int idx = blockIdx.x * 256 + threadIdx.x;   // [a][b][i] flat
    const int i  = idx % NPX;
    const int ab = idx / NPX;
    const int b  = ab & 7;
    const int a  = ab >> 3;
    float d = 0.f;
    #pragma unroll
    for (int c = 0; c < 18; c++)
        d += pd[((size_t)ab * 18 + c) * NPX + i];
    const float m = -__log2f(d);

    const unsigned short mh = bf16r(m);
    __hip_bfloat16 hb; *(unsigned short*)&hb = mh;
    const unsigned short ml = bf16r(m - __bfloat162float(hb));

    unsigned short* qb = (unsigned short*)(ws + (a ? WS_QB2 : WS_QB1));
    const size_t rbase = (size_t)(b * NPX + i) * 16;
    qb[rbase + 8] = mh;
    qb[rbase + 9] = ml;
}

// ---------------------------------------------------------------------------
// Kernel 4: output, all-MFMA, split-K over i (4 quarters), register prefetch,
// atomicAdd epilogue. grid (36 jt, 8 b, 8 z), z = o*4 + ihalf; block 256
// (4 waves), 9 chunks of 64 i. pt stride 72 (LDS 18432 B -> 8 blocks/CU,
// 32 waves = CU max). P pack via v_perm (3 inst / 2 vals). Pointers advance
// by constants (no per-iter 64-bit mul). S-MFMA includes the -log2(D_i)
// fold via qb slots 8/9 x kb slots 8/9 -> P = exp2(acc) pre-normalized.
// ---------------------------------------------------------------------------
__global__ __launch_bounds__(256) void out_kernel(
    const float* __restrict__ gamma, const float* __restrict__ beta,
    const float* __restrict__ ws, float* __restrict__ out)
{
    const int t  = threadIdx.x;
    const int jt = blockIdx.x;      // 0..35
    const int b  = blockIdx.y;
    const int z  = blockIdx.z;      // o*4 + ihalf
    const int o  = z >> 2;
    const int ihalf = z & 3;

    const int a = o ? 0 : 1;        // attn used: o1<-attn2, o2<-attn1
    const unsigned short* qb = (const unsigned short*)(ws + (a ? WS_QB2 : WS_QB1));
    const unsigned short* kb = (const unsigned short*)(ws + (a ? WS_KB2 : WS_KB1));
    const unsigned short* v  = (const unsigned short*)(ws + (o ? WS_V2 : WS_V1));
    const float  scale = o ? beta[0] : gamma[0];

    __shared__ unsigned short vt[64][72];   // v[c][i]
    __shared__ unsigned short pt[64][72];   // P[j][i]

    const int j0   = jt * 64;
    const int lane = t & 63;
    const int w    = t >> 6;
    const int n    = lane & 31;
    const int h    = lane >> 5;
    const int jh   = w & 1;
    const int ihq  = w >> 1;
    const int cbase = 32 * (w & 1);
    const int jbase = 32 * (w >> 1);

    const short8 kfrag = *(const short8*)(kb + (size_t)(b * NPX + j0 + 32 * jh + n) * 16 + h * 8);

    // staging indices (2 x 16B segments per thread)
    const int c0 = t >> 3, s80 = (t & 7) * 8;
    const int c1 = (t + 256) >> 3, s81 = ((t + 256) & 7) * 8;

    const int ibase = ihalf * 576;
    const unsigned short* vp0 = v + ((size_t)b * CCH + c0) * NPX + ibase + s80;
    const unsigned short* vp1 = v + ((size_t)b * CCH + c1) * NPX + ibase + s81;
    const unsigned short* qp  = qb + (size_t)(b * NPX + ibase + 32 * ihq + n) * 16 + h * 8;

    // prefetch chunk 0
    float4 vpre0 = *(const float4*)vp0;
    float4 vpre1 = *(const float4*)vp1;
    short8 qpre  = *(const short8*)qp;

    float16t oacc = {};

    for (int it = 0; it < 9; it++) {
        // issue next chunk's loads before the barriers
        vp0 += 64; vp1 += 64; qp += 64 * 16;
        float4 vn0 = vpre0, vn1 = vpre1;
        short8 qn = qpre;
        if (it + 1 < 9) {
            vn0 = *(const float4*)vp0;
            vn1 = *(const float4*)vp1;
            qn  = *(const short8*)qp;
        }

        __syncthreads();            // prior PV reads of vt/pt complete

        *(float4*)&vt[c0][s80] = vpre0;
        *(float4*)&vt[c1][s81] = vpre1;

        float16t sc = {};
        sc = __builtin_amdgcn_mfma_f32_32x32x16_bf16(qpre, kfrag, sc, 0, 0, 0);

        #pragma unroll
        for (int gq = 0; gq < 4; gq++) {
            const int ibl = 32 * ihq + 8 * gq + 4 * h;
            uint2 pk;
            pk.x = pack_bf16(exp2f(sc[gq * 4 + 0]), exp2f(sc[gq * 4 + 1]));
            pk.y = pack_bf16(exp2f(sc[gq * 4 + 2]), exp2f(sc[gq * 4 + 3]));
            *(uint2*)&pt[32 * jh + n][ibl] = pk;
        }
        __syncthreads();            // vt + pt ready

        #pragma unroll
        for (int kk = 0; kk < 4; kk++) {
            const short8 afrag = *(const short8*)&vt[cbase + n][kk * 16 + h * 8];
            const short8 bfrag = *(const short8*)&pt[jbase + n][kk * 16 + h * 8];
            oacc = __builtin_amdgcn_mfma_f32_32x32x16_bf16(afrag, bfrag, oacc, 0, 0, 0);
        }

        vpre0 = vn0; vpre1 = vn1; qpre = qn;
    }

    // epilogue: out += scale*acc (residual already in out). 32-bit indexing.
    float* outp = out + (o ? BCN : 0) + (b * CCH + cbase) * NPX + j0 + jbase + n;
    #pragma unroll
    for (int r = 0; r < 16; r++) {
        const int row = (r & 3) + 8 * (r >> 2) + 4 * h;
        atomicAdd(outp + row * NPX, oacc[r] * scale);
    }
}

// ---------------------------------------------------------------------------
extern "C" void kernel_launch(void* const* d_in, const int* in_sizes, int n_in,
                              void* d_out, int out_size, void* d_ws, size_t ws_size,
                              hipStream_t stream)
{
    const float* x1   = (const float*)d_in[0];
    const float* x2   = (const float*)d_in[1];
    const float* Wqk1 = (const float*)d_in[2];
    const float* bqk1 = (const float*)d_in[3];
    const float* Wqk2 = (const float*)d_in[4];
    const float* bqk2 = (const float*)d_in[5];
    const float* Wv1  = (const float*)d_in[6];
    const float* bv1  = (const float*)d_in[7];
    const float* Wv2  = (const float*)d_in[8];
    const float* bv2  = (const float*)d_in[9];
    const float* gamma = (const float*)d_in[10];
    const float* beta  = (const float*)d_in[11];
    float* out = (float*)d_out;
    float* ws  = (float*)d_ws;

    proj_kernel<<<dim3(72, 8), 256, 0, stream>>>(
        x1, x2, Wqk1, bqk1, Wqk2, bqk2, Wv1, bv1, Wv2, bv2, ws, out);
    stats_kernel<<<dim3(18, 4, 16), 256, 0, stream>>>(ws);
    merge_fold<<<dim3(144), 256, 0, stream>>>(ws);
    out_kernel<<<dim3(36, 8, 8), 256, 0, stream>>>(gamma, beta, ws, out);
}

// Round 11
// 149.217 us; speedup vs baseline: 1.0568x; 1.0568x over previous
//
#include <hip/hip_runtime.h>
#include <hip/hip_bf16.h>

// Problem constants
#define NB   8
#define CCH  64
#define CR8  8
#define NPX  2304           // 48*48
#define BCN  (NB*CCH*NPX)   // 1179648
#define LOG2E 1.4426950408889634f

typedef short  short8   __attribute__((ext_vector_type(8)));
typedef unsigned short ushort8t __attribute__((ext_vector_type(8)));
typedef float  float4t  __attribute__((ext_vector_type(4)));
typedef float  float16t __attribute__((ext_vector_type(16)));

// native v_exp_f32 (1 inst; ~1 ulp; valid for our |x| < ~50 range).
// exp2f() without -ffast-math is the OCML precise wrapper (~6-8 VALU inst).
static __device__ __forceinline__ float fexp2(float x) {
    return __builtin_amdgcn_exp2f(x);
}
// round-half-up bf16 from f32: (u + 0x8000) >> 16  (<=1 ulp vs RNE)
static __device__ __forceinline__ unsigned short bf16r(float f) {
    return (unsigned short)((__float_as_uint(f) + 0x8000u) >> 16);
}
// pack two f32 -> two bf16 in one dword: [hi16(hi) : hi16(lo)], 3 VALU inst
static __device__ __forceinline__ unsigned int pack_bf16(float lo, float hi) {
    const unsigned int ul = __float_as_uint(lo) + 0x8000u;
    const unsigned int uh = __float_as_uint(hi) + 0x8000u;
    return __builtin_amdgcn_perm(uh, ul, 0x07060302u);
}
// 8 floats -> short8 bf16 fragment (4 perms)
static __device__ __forceinline__ short8 pack8(const float* f) {
    union { unsigned int u[4]; short8 s; } r;
    #pragma unroll
    for (int j = 0; j < 4; j++) r.u[j] = pack_bf16(f[2*j], f[2*j+1]);
    return r.s;
}

// Workspace layout (float offsets)
// qb/kb: bf16 [b][i][16] rows. qb: c 0..7 = q*log2e, slots 8/9 get
// -log2(D_i) hi/lo AFTER stats (merge_fold); kb: c 0..7 = k, slots 8/9 = 1.0.
// The S-MFMA in out_kernel then yields log2(P_normalized) directly.
#define WS_QB1 0
#define WS_KB1 (WS_QB1 + 147456)
#define WS_QB2 (WS_KB1 + 147456)
#define WS_KB2 (WS_QB2 + 147456)
#define WS_V1  (WS_KB2 + 147456)        // bf16 [b][c][i], unscaled
#define WS_V2  (WS_V1 + BCN/2)
#define WS_PD  (WS_V2 + BCN/2)          // partial denom [a][b][jsb=18][i] fp32

// ---------------------------------------------------------------------------
// Kernel 1: projections as MFMA GEMM. M=160 rows (qk1,qk2,v1,v2), N=px, K=64.
// grid (72 pxtiles of 32, 8 b), block 256 = 4 independent waves, NO LDS,
// NO barriers. Also writes out = x residual-init. kb pad slots 8,9 = 1.0.
// ---------------------------------------------------------------------------
__global__ __launch_bounds__(256) void proj_kernel(
    const float* __restrict__ x1, const float* __restrict__ x2,
    const float* __restrict__ Wqk1, const float* __restrict__ bqk1,
    const float* __restrict__ Wqk2, const float* __restrict__ bqk2,
    const float* __restrict__ Wv1,  const float* __restrict__ bv1,
    const float* __restrict__ Wv2,  const float* __restrict__ bv2,
    float* __restrict__ ws, float* __restrict__ out)
{
    const int t    = threadIdx.x;
    const int lane = t & 63;
    const int w    = t >> 6;
    const int n16  = lane & 15;
    const int c4   = lane >> 4;
    const int nt   = w & 1;
    const int mh   = w >> 1;
    const int b    = blockIdx.y;
    const int px   = blockIdx.x * 32 + nt * 16 + n16;

    const float* xsb[2];
    xsb[0] = x1 + ((size_t)b * CCH) * NPX + px;
    xsb[1] = x2 + ((size_t)b * CCH) * NPX + px;

    float xr[2][16];
    short8 bfrag[2][2];
    #pragma unroll
    for (int st = 0; st < 2; st++) {
        #pragma unroll
        for (int ch = 0; ch < 2; ch++) {
            #pragma unroll
            for (int j = 0; j < 8; j++)
                xr[st][ch * 8 + j] = xsb[st][(ch * 32 + c4 * 8 + j) * NPX];
            bfrag[st][ch] = pack8(&xr[st][ch * 8]);
        }
    }

    if (mh == 0) {
        #pragma unroll
        for (int st = 0; st < 2; st++) {
            float* outs = out + (st ? (size_t)BCN : 0);
            #pragma unroll
            for (int e = 0; e < 16; e++) {
                const int ch = (e >> 3) * 32 + c4 * 8 + (e & 7);
                outs[((size_t)b * CCH + ch) * NPX + px] = xr[st][e];
            }
        }
    }

    float4t acc[5];
    #pragma unroll
    for (int mt = 0; mt < 5; mt++) { acc[mt][0]=0.f; acc[mt][1]=0.f; acc[mt][2]=0.f; acc[mt][3]=0.f; }

    #pragma unroll
    for (int mt = 0; mt < 5; mt++) {
        const int mi  = mh * 5 + mt;
        const int isqk = (mi < 2);
        const int st  = isqk ? (mi & 1) : (mi >= 6);
        const float* Wb;
        int rowbase;
        if (isqk) { Wb = (mi == 0) ? Wqk1 : Wqk2; rowbase = 0; }
        else      { Wb = (mi >= 6) ? Wv2 : Wv1; rowbase = (mi - (mi >= 6 ? 6 : 2)) * 16; }
        const float* wrow = Wb + (size_t)(rowbase + n16) * 64 + c4 * 8;

        const short8 bf0 = st ? bfrag[1][0] : bfrag[0][0];
        const short8 bf1 = st ? bfrag[1][1] : bfrag[0][1];

        #pragma unroll
        for (int ch = 0; ch < 2; ch++) {
            float fa[8];
            const float4 a0 = *(const float4*)(wrow + ch * 32);
            const float4 a1 = *(const float4*)(wrow + ch * 32 + 4);
            fa[0] = a0.x; fa[1] = a0.y; fa[2] = a0.z; fa[3] = a0.w;
            fa[4] = a1.x; fa[5] = a1.y; fa[6] = a1.z; fa[7] = a1.w;
            acc[mt] = __builtin_amdgcn_mfma_f32_16x16x32_bf16(
                pack8(fa), ch ? bf1 : bf0, acc[mt], 0, 0, 0);
        }
    }

    #pragma unroll
    for (int mt = 0; mt < 5; mt++) {
        const int mi = mh * 5 + mt;
        if (mi < 2) {                       // qk tile (wave-uniform branch)
            const int st = mi & 1;
            const float* bqk = st ? bqk2 : bqk1;
            unsigned short* qb = (unsigned short*)(ws + (st ? WS_QB2 : WS_QB1));
            unsigned short* kb = (unsigned short*)(ws + (st ? WS_KB2 : WS_KB1));
            const size_t rbase = (size_t)(b * NPX + px) * 16;
            #pragma unroll
            for (int r = 0; r < 4; r++) {
                const int oc = c4 * 4 + r;
                const float val = acc[mt][r] + bqk[oc];
                if (oc < 8)
                    qb[rbase + oc] = bf16r(val * LOG2E);
                else
                    kb[rbase + (oc - 8)] = bf16r(val);
            }
            ushort8t zq, zk;
            #pragma unroll
            for (int e = 0; e < 8; e++) { zq[e] = 0; zk[e] = 0; }
            zk[0] = 0x3F80; zk[1] = 0x3F80;   // kb slots 8,9 = bf16(1.0)
            if (c4 == 0) *(ushort8t*)(qb + rbase + 8) = zq;
            if (c4 == 2) *(ushort8t*)(kb + rbase + 8) = zk;
        } else {                            // v tile
            const int st = (mi >= 6);
            const int vt_ = mi - (st ? 6 : 2);
            const float* bv = st ? bv2 : bv1;
            unsigned short* v = (unsigned short*)(ws + (st ? WS_V2 : WS_V1));
            #pragma unroll
            for (int r = 0; r < 4; r++) {
                const int oc = vt_ * 16 + c4 * 4 + r;
                const float val = acc[mt][r] + bv[oc];
                v[((size_t)b * CCH + oc) * NPX + px] = bf16r(val);
            }
        }
    }
}

// ---------------------------------------------------------------------------
// Kernel 2: softmax denominators via MFMA, barrier-free inner loop with
// 1-deep qfrag prefetch, pointer-incremented addressing, native v_exp_f32.
// grid (18 jsb, 4 iq, 16 ab), block 256.
// ---------------------------------------------------------------------------
__global__ __launch_bounds__(256) void stats_kernel(float* __restrict__ ws)
{
    const int t  = threadIdx.x;
    const int w  = t >> 6;
    const int n  = t & 31;
    const int h  = (t & 63) >> 5;
    const int jsb = blockIdx.x;     // 0..17
    const int iq  = blockIdx.y;     // 0..3
    const int ab  = blockIdx.z;     // a*8+b
    const int b   = ab & 7;
    const int a   = ab >> 3;

    const unsigned short* qb = (const unsigned short*)(ws + (a ? WS_QB2 : WS_QB1));
    const unsigned short* kb = (const unsigned short*)(ws + (a ? WS_KB2 : WS_KB1));
    float* pd = ws + WS_PD;

    __shared__ float red[4][576];

    const int j = jsb * 128 + w * 32 + n;
    const short8 kfrag = *(const short8*)(kb + (size_t)(b * NPX + j) * 16 + h * 8);

    const unsigned short* qp = qb + (size_t)(b * NPX + iq * 576 + n) * 16 + h * 8;
    short8 qf = *(const short8*)qp;

    for (int ib = 0; ib < 18; ib++) {
        qp += 512;                  // next 32-row i-block
        short8 qn = qf;
        if (ib + 1 < 18) qn = *(const short8*)qp;
        float16t acc = {};
        acc = __builtin_amdgcn_mfma_f32_32x32x16_bf16(kfrag, qf, acc, 0, 0, 0);
        float s0 = 0.f, s1 = 0.f, s2 = 0.f, s3 = 0.f;
        #pragma unroll
        for (int r = 0; r < 4; r++) {
            s0 += fexp2(acc[4 * r + 0]);
            s1 += fexp2(acc[4 * r + 1]);
            s2 += fexp2(acc[4 * r + 2]);
            s3 += fexp2(acc[4 * r + 3]);
        }
        float ssum = (s0 + s1) + (s2 + s3);
        ssum += __shfl_xor(ssum, 32);
        if (h == 0) red[w][ib * 32 + n] = ssum;
        qf = qn;
    }
    __syncthreads();
    for (int idx = t; idx < 576; idx += 256)
        pd[((size_t)ab * 18 + jsb) * NPX + iq * 576 + idx] =
            red[0][idx] + red[1][idx] + red[2][idx] + red[3][idx];
}

// ---------------------------------------------------------------------------
// Kernel 3: merge 18 partials -> m = -log2(D_i), folded into qb slots 8/9
// (hi/lo bf16 split, error ~2^-17). grid (144), block 256. Tiny.
// ---------------------------------------------------------------------------
__global__ __launch_bounds__(256) void merge_fold(float* __restrict__ ws)
{
    const float* pd = ws + WS_PD;
    const int idx = blockIdx.x * 256 + threadIdx.x;   // [a][b][i] flat
    const int i  = idx % NPX;
    const int ab = idx / NPX;
    const int b  = ab & 7;
    const int a  = ab >> 3;
    float d = 0.f;
    #pragma unroll
    for (int c = 0; c < 18; c++)
        d += pd[((size_t)ab * 18 + c) * NPX + i];
    const float m = -__log2f(d);

    const unsigned short mh = bf16r(m);
    __hip_bfloat16 hb; *(unsigned short*)&hb = mh;
    const unsigned short ml = bf16r(m - __bfloat162float(hb));

    unsigned short* qb = (unsigned short*)(ws + (a ? WS_QB2 : WS_QB1));
    const size_t rbase = (size_t)(b * NPX + i) * 16;
    qb[rbase + 8] = mh;
    qb[rbase + 9] = ml;
}

// ---------------------------------------------------------------------------
// Kernel 4: output, all-MFMA, split-K over i (4 quarters), register prefetch,
// atomicAdd epilogue, native v_exp_f32. grid (36 jt, 8 b, 8 z), z = o*4 +
// ihalf; block 256 (4 waves), 9 chunks of 64 i. pt stride 72 (LDS 18432 B).
// P pack via v_perm. S-MFMA includes the -log2(D_i) fold via qb slots 8/9
// x kb slots 8/9 -> P = exp2(acc) pre-normalized.
// ---------------------------------------------------------------------------
__global__ __launch_bounds__(256) void out_kernel(
    const float* __restrict__ gamma, const float* __restrict__ beta,
    const float* __restrict__ ws, float* __restrict__ out)
{
    const int t  = threadIdx.x;
    const int jt = blockIdx.x;      // 0..35
    const int b  = blockIdx.y;
    const int z  = blockIdx.z;      // o*4 + ihalf
    const int o  = z >> 2;
    const int ihalf = z & 3;

    const int a = o ? 0 : 1;        // attn used: o1<-attn2, o2<-attn1
    const unsigned short* qb = (const unsigned short*)(ws + (a ? WS_QB2 : WS_QB1));
    const unsigned short* kb = (const unsigned short*)(ws + (a ? WS_KB2 : WS_KB1));
    const unsigned short* v  = (const unsigned short*)(ws + (o ? WS_V2 : WS_V1));
    const float  scale = o ? beta[0] : gamma[0];

    __shared__ unsigned short vt[64][72];   // v[c][i]
    __shared__ unsigned short pt[64][72];   // P[j][i]

    const int j0   = jt * 64;
    const int lane = t & 63;
    const int w    = t >> 6;
    const int n    = lane & 31;
    const int h    = lane >> 5;
    const int jh   = w & 1;
    const int ihq  = w >> 1;
    const int cbase = 32 * (w & 1);
    const int jbase = 32 * (w >> 1);

    const short8 kfrag = *(const short8*)(kb + (size_t)(b * NPX + j0 + 32 * jh + n) * 16 + h * 8);

    // staging indices (2 x 16B segments per thread)
    const int c0 = t >> 3, s80 = (t & 7) * 8;
    const int c1 = (t + 256) >> 3, s81 = ((t + 256) & 7) * 8;

    const int ibase = ihalf * 576;
    const unsigned short* vp0 = v + ((size_t)b * CCH + c0) * NPX + ibase + s80;
    const unsigned short* vp1 = v + ((size_t)b * CCH + c1) * NPX + ibase + s81;
    const unsigned short* qp  = qb + (size_t)(b * NPX + ibase + 32 * ihq + n) * 16 + h * 8;

    // prefetch chunk 0
    float4 vpre0 = *(const float4*)vp0;
    float4 vpre1 = *(const float4*)vp1;
    short8 qpre  = *(const short8*)qp;

    float16t oacc = {};

    for (int it = 0; it < 9; it++) {
        // issue next chunk's loads before the barriers
        vp0 += 64; vp1 += 64; qp += 64 * 16;
        float4 vn0 = vpre0, vn1 = vpre1;
        short8 qn = qpre;
        if (it + 1 < 9) {
            vn0 = *(const float4*)vp0;
            vn1 = *(const float4*)vp1;
            qn  = *(const short8*)qp;
        }

        __syncthreads();            // prior PV reads of vt/pt complete

        *(float4*)&vt[c0][s80] = vpre0;
        *(float4*)&vt[c1][s81] = vpre1;

        float16t sc = {};
        sc = __builtin_amdgcn_mfma_f32_32x32x16_bf16(qpre, kfrag, sc, 0, 0, 0);

        #pragma unroll
        for (int gq = 0; gq < 4; gq++) {
            const int ibl = 32 * ihq + 8 * gq + 4 * h;
            uint2 pk;
            pk.x = pack_bf16(fexp2(sc[gq * 4 + 0]), fexp2(sc[gq * 4 + 1]));
            pk.y = pack_bf16(fexp2(sc[gq * 4 + 2]), fexp2(sc[gq * 4 + 3]));
            *(uint2*)&pt[32 * jh + n][ibl] = pk;
        }
        __syncthreads();            // vt + pt ready

        #pragma unroll
        for (int kk = 0; kk < 4; kk++) {
            const short8 afrag = *(const short8*)&vt[cbase + n][kk * 16 + h * 8];
            const short8 bfrag = *(const short8*)&pt[jbase + n][kk * 16 + h * 8];
            oacc = __builtin_amdgcn_mfma_f32_32x32x16_bf16(afrag, bfrag, oacc, 0, 0, 0);
        }

        vpre0 = vn0; vpre1 = vn1; qpre = qn;
    }

    // epilogue: out += scale*acc (residual already in out). 32-bit indexing.
    float* outp = out + (o ? BCN : 0) + (b * CCH + cbase) * NPX + j0 + jbase + n;
    #pragma unroll
    for (int r = 0; r < 16; r++) {
        const int row = (r & 3) + 8 * (r >> 2) + 4 * h;
        atomicAdd(outp + row * NPX, oacc[r] * scale);
    }
}

// ---------------------------------------------------------------------------
extern "C" void kernel_launch(void* const* d_in, const int* in_sizes, int n_in,
                              void* d_out, int out_size, void* d_ws, size_t ws_size,
                              hipStream_t stream)
{
    const float* x1   = (const float*)d_in[0];
    const float* x2   = (const float*)d_in[1];
    const float* Wqk1 = (const float*)d_in[2];
    const float* bqk1 = (const float*)d_in[3];
    const float* Wqk2 = (const float*)d_in[4];
    const float* bqk2 = (const float*)d_in[5];
    const float* Wv1  = (const float*)d_in[6];
    const float* bv1  = (const float*)d_in[7];
    const float* Wv2  = (const float*)d_in[8];
    const float* bv2  = (const float*)d_in[9];
    const float* gamma = (const float*)d_in[10];
    const float* beta  = (const float*)d_in[11];
    float* out = (float*)d_out;
    float* ws  = (float*)d_ws;

    proj_kernel<<<dim3(72, 8), 256, 0, stream>>>(
        x1, x2, Wqk1, bqk1, Wqk2, bqk2, Wv1, bv1, Wv2, bv2, ws, out);
    stats_kernel<<<dim3(18, 4, 16), 256, 0, stream>>>(ws);
    merge_fold<<<dim3(144), 256, 0, stream>>>(ws);
    out_kernel<<<dim3(36, 8, 8), 256, 0, stream>>>(gamma, beta, ws, out);
}

// Round 12
// 144.069 us; speedup vs baseline: 1.0945x; 1.0357x over previous
//
#include <hip/hip_runtime.h>
#include <hip/hip_bf16.h>

// Problem constants
#define NB   8
#define CCH  64
#define CR8  8
#define NPX  2304           // 48*48
#define BCN  (NB*CCH*NPX)   // 1179648
#define LOG2E 1.4426950408889634f

typedef short  short8   __attribute__((ext_vector_type(8)));
typedef unsigned short ushort8t __attribute__((ext_vector_type(8)));
typedef float  float4t  __attribute__((ext_vector_type(4)));
typedef float  float16t __attribute__((ext_vector_type(16)));

// native v_exp_f32 (1 inst; ~1 ulp; valid for our |x| < ~50 range).
static __device__ __forceinline__ float fexp2(float x) {
    return __builtin_amdgcn_exp2f(x);
}
// round-half-up bf16 from f32: (u + 0x8000) >> 16  (<=1 ulp vs RNE)
static __device__ __forceinline__ unsigned short bf16r(float f) {
    return (unsigned short)((__float_as_uint(f) + 0x8000u) >> 16);
}
// pack two f32 -> two bf16 in one dword: [hi16(hi) : hi16(lo)], 3 VALU inst
static __device__ __forceinline__ unsigned int pack_bf16(float lo, float hi) {
    const unsigned int ul = __float_as_uint(lo) + 0x8000u;
    const unsigned int uh = __float_as_uint(hi) + 0x8000u;
    return __builtin_amdgcn_perm(uh, ul, 0x07060302u);
}
// 8 floats -> short8 bf16 fragment (4 perms)
static __device__ __forceinline__ short8 pack8(const float* f) {
    union { unsigned int u[4]; short8 s; } r;
    #pragma unroll
    for (int j = 0; j < 4; j++) r.u[j] = pack_bf16(f[2*j], f[2*j+1]);
    return r.s;
}

// Workspace layout (float offsets)
// qb/kb: bf16 [b][i][16] rows. qb: c 0..7 = q*log2e, slots 8/9 get
// -log2(D_i) hi/lo AFTER stats (merge_fold); kb: c 0..7 = k, slots 8/9 = 1.0.
// The S-MFMA in out_kernel then yields log2(P_normalized) directly.
#define WS_QB1 0
#define WS_KB1 (WS_QB1 + 147456)
#define WS_QB2 (WS_KB1 + 147456)
#define WS_KB2 (WS_QB2 + 147456)
#define WS_V1  (WS_KB2 + 147456)        // bf16 [b][c][i], unscaled
#define WS_V2  (WS_V1 + BCN/2)
#define WS_PD  (WS_V2 + BCN/2)          // partial denom [a][b][jsb=18][i] fp32

// ---------------------------------------------------------------------------
// Kernel 1: projections as MFMA GEMM. M=160 rows (qk1,qk2,v1,v2), N=px, K=64.
// grid (72 pxtiles of 32, 8 b), block 256 = 4 independent waves, NO LDS,
// NO barriers. Also writes out = x residual-init. kb pad slots 8,9 = 1.0.
// ---------------------------------------------------------------------------
__global__ __launch_bounds__(256) void proj_kernel(
    const float* __restrict__ x1, const float* __restrict__ x2,
    const float* __restrict__ Wqk1, const float* __restrict__ bqk1,
    const float* __restrict__ Wqk2, const float* __restrict__ bqk2,
    const float* __restrict__ Wv1,  const float* __restrict__ bv1,
    const float* __restrict__ Wv2,  const float* __restrict__ bv2,
    float* __restrict__ ws, float* __restrict__ out)
{
    const int t    = threadIdx.x;
    const int lane = t & 63;
    const int w    = t >> 6;
    const int n16  = lane & 15;
    const int c4   = lane >> 4;
    const int nt   = w & 1;
    const int mh   = w >> 1;
    const int b    = blockIdx.y;
    const int px   = blockIdx.x * 32 + nt * 16 + n16;

    const float* xsb[2];
    xsb[0] = x1 + ((size_t)b * CCH) * NPX + px;
    xsb[1] = x2 + ((size_t)b * CCH) * NPX + px;

    float xr[2][16];
    short8 bfrag[2][2];
    #pragma unroll
    for (int st = 0; st < 2; st++) {
        #pragma unroll
        for (int ch = 0; ch < 2; ch++) {
            #pragma unroll
            for (int j = 0; j < 8; j++)
                xr[st][ch * 8 + j] = xsb[st][(ch * 32 + c4 * 8 + j) * NPX];
            bfrag[st][ch] = pack8(&xr[st][ch * 8]);
        }
    }

    if (mh == 0) {
        #pragma unroll
        for (int st = 0; st < 2; st++) {
            float* outs = out + (st ? (size_t)BCN : 0);
            #pragma unroll
            for (int e = 0; e < 16; e++) {
                const int ch = (e >> 3) * 32 + c4 * 8 + (e & 7);
                outs[((size_t)b * CCH + ch) * NPX + px] = xr[st][e];
            }
        }
    }

    float4t acc[5];
    #pragma unroll
    for (int mt = 0; mt < 5; mt++) { acc[mt][0]=0.f; acc[mt][1]=0.f; acc[mt][2]=0.f; acc[mt][3]=0.f; }

    #pragma unroll
    for (int mt = 0; mt < 5; mt++) {
        const int mi  = mh * 5 + mt;
        const int isqk = (mi < 2);
        const int st  = isqk ? (mi & 1) : (mi >= 6);
        const float* Wb;
        int rowbase;
        if (isqk) { Wb = (mi == 0) ? Wqk1 : Wqk2; rowbase = 0; }
        else      { Wb = (mi >= 6) ? Wv2 : Wv1; rowbase = (mi - (mi >= 6 ? 6 : 2)) * 16; }
        const float* wrow = Wb + (size_t)(rowbase + n16) * 64 + c4 * 8;

        const short8 bf0 = st ? bfrag[1][0] : bfrag[0][0];
        const short8 bf1 = st ? bfrag[1][1] : bfrag[0][1];

        #pragma unroll
        for (int ch = 0; ch < 2; ch++) {
            float fa[8];
            const float4 a0 = *(const float4*)(wrow + ch * 32);
            const float4 a1 = *(const float4*)(wrow + ch * 32 + 4);
            fa[0] = a0.x; fa[1] = a0.y; fa[2] = a0.z; fa[3] = a0.w;
            fa[4] = a1.x; fa[5] = a1.y; fa[6] = a1.z; fa[7] = a1.w;
            acc[mt] = __builtin_amdgcn_mfma_f32_16x16x32_bf16(
                pack8(fa), ch ? bf1 : bf0, acc[mt], 0, 0, 0);
        }
    }

    #pragma unroll
    for (int mt = 0; mt < 5; mt++) {
        const int mi = mh * 5 + mt;
        if (mi < 2) {                       // qk tile (wave-uniform branch)
            const int st = mi & 1;
            const float* bqk = st ? bqk2 : bqk1;
            unsigned short* qb = (unsigned short*)(ws + (st ? WS_QB2 : WS_QB1));
            unsigned short* kb = (unsigned short*)(ws + (st ? WS_KB2 : WS_KB1));
            const size_t rbase = (size_t)(b * NPX + px) * 16;
            #pragma unroll
            for (int r = 0; r < 4; r++) {
                const int oc = c4 * 4 + r;
                const float val = acc[mt][r] + bqk[oc];
                if (oc < 8)
                    qb[rbase + oc] = bf16r(val * LOG2E);
                else
                    kb[rbase + (oc - 8)] = bf16r(val);
            }
            ushort8t zq, zk;
            #pragma unroll
            for (int e = 0; e < 8; e++) { zq[e] = 0; zk[e] = 0; }
            zk[0] = 0x3F80; zk[1] = 0x3F80;   // kb slots 8,9 = bf16(1.0)
            if (c4 == 0) *(ushort8t*)(qb + rbase + 8) = zq;
            if (c4 == 2) *(ushort8t*)(kb + rbase + 8) = zk;
        } else {                            // v tile
            const int st = (mi >= 6);
            const int vt_ = mi - (st ? 6 : 2);
            const float* bv = st ? bv2 : bv1;
            unsigned short* v = (unsigned short*)(ws + (st ? WS_V2 : WS_V1));
            #pragma unroll
            for (int r = 0; r < 4; r++) {
                const int oc = vt_ * 16 + c4 * 4 + r;
                const float val = acc[mt][r] + bv[oc];
                v[((size_t)b * CCH + oc) * NPX + px] = bf16r(val);
            }
        }
    }
}

// ---------------------------------------------------------------------------
// Kernel 2: softmax denominators via MFMA, barrier-free inner loop with
// 1-deep qfrag prefetch. i-split x8: grid (18 jsb, 8 iq, 16 ab) = 2304
// blocks (9/CU), 9 i-blocks of 32 each (half the serial chain of r11).
// ---------------------------------------------------------------------------
__global__ __launch_bounds__(256) void stats_kernel(float* __restrict__ ws)
{
    const int t  = threadIdx.x;
    const int w  = t >> 6;
    const int n  = t & 31;
    const int h  = (t & 63) >> 5;
    const int jsb = blockIdx.x;     // 0..17
    const int iq  = blockIdx.y;     // 0..7
    const int ab  = blockIdx.z;     // a*8+b
    const int b   = ab & 7;
    const int a   = ab >> 3;

    const unsigned short* qb = (const unsigned short*)(ws + (a ? WS_QB2 : WS_QB1));
    const unsigned short* kb = (const unsigned short*)(ws + (a ? WS_KB2 : WS_KB1));
    float* pd = ws + WS_PD;

    __shared__ float red[4][288];

    const int j = jsb * 128 + w * 32 + n;
    const short8 kfrag = *(const short8*)(kb + (size_t)(b * NPX + j) * 16 + h * 8);

    const unsigned short* qp = qb + (size_t)(b * NPX + iq * 288 + n) * 16 + h * 8;
    short8 qf = *(const short8*)qp;

    for (int ib = 0; ib < 9; ib++) {
        qp += 512;                  // next 32-row i-block
        short8 qn = qf;
        if (ib + 1 < 9) qn = *(const short8*)qp;
        float16t acc = {};
        acc = __builtin_amdgcn_mfma_f32_32x32x16_bf16(kfrag, qf, acc, 0, 0, 0);
        float s0 = 0.f, s1 = 0.f, s2 = 0.f, s3 = 0.f;
        #pragma unroll
        for (int r = 0; r < 4; r++) {
            s0 += fexp2(acc[4 * r + 0]);
            s1 += fexp2(acc[4 * r + 1]);
            s2 += fexp2(acc[4 * r + 2]);
            s3 += fexp2(acc[4 * r + 3]);
        }
        float ssum = (s0 + s1) + (s2 + s3);
        ssum += __shfl_xor(ssum, 32);
        if (h == 0) red[w][ib * 32 + n] = ssum;
        qf = qn;
    }
    __syncthreads();
    for (int idx = t; idx < 288; idx += 256)
        pd[((size_t)ab * 18 + jsb) * NPX + iq * 288 + idx] =
            red[0][idx] + red[1][idx] + red[2][idx] + red[3][idx];
}

// ---------------------------------------------------------------------------
// Kernel 3: merge 18 partials -> m = -log2(D_i) into qb slots 8/9.
// Parallelized: grid (36 igrp, 16 ab), block 256 = 64 i x 4 partial-groups;
// each thread sums 5 strided partials (vs 18 serial in r11), LDS reduce.
// ---------------------------------------------------------------------------
__global__ __launch_bounds__(256) void merge_fold(float* __restrict__ ws)
{
    const float* pd = ws + WS_PD;
    const int t  = threadIdx.x;
    const int il = t & 63;
    const int pg = t >> 6;          // partial group 0..3
    const int i  = blockIdx.x * 64 + il;
    const int ab = blockIdx.y;
    const int b  = ab & 7;
    const int a  = ab >> 3;

    __shared__ float red[4][64];

    const float* pb = pd + (size_t)ab * 18 * NPX + i;
    float d = 0.f;
    #pragma unroll
    for (int c = pg; c < 18; c += 4)
        d += pb[(size_t)c * NPX];
    red[pg][il] = d;
    __syncthreads();

    if (t < 64) {
        const float dt = (red[0][t] + red[1][t]) + (red[2][t] + red[3][t]);
        const float m = -__log2f(dt);
        const unsigned short mh = bf16r(m);
        __hip_bfloat16 hb; *(unsigned short*)&hb = mh;
        const unsigned short ml = bf16r(m - __bfloat162float(hb));
        unsigned short* qb = (unsigned short*)(ws + (a ? WS_QB2 : WS_QB1));
        const size_t rbase = (size_t)(b * NPX + blockIdx.x * 64 + t) * 16;
        qb[rbase + 8] = mh;
        qb[rbase + 9] = ml;
    }
}

// ---------------------------------------------------------------------------
// Kernel 4: output, all-MFMA, split-K over i (4 quarters), register prefetch,
// atomicAdd epilogue, native v_exp_f32. grid (36 jt, 8 b, 8 z), z = o*4 +
// ihalf; block 256 (4 waves), 9 chunks of 64 i. pt stride 72 (LDS 18432 B).
// S-MFMA includes the -log2(D_i) fold via qb slots 8/9 x kb slots 8/9.
// ---------------------------------------------------------------------------
__global__ __launch_bounds__(256) void out_kernel(
    const float* __restrict__ gamma, const float* __restrict__ beta,
    const float* __restrict__ ws, float* __restrict__ out)
{
    const int t  = threadIdx.x;
    const int jt = blockIdx.x;      // 0..35
    const int b  = blockIdx.y;
    const int z  = blockIdx.z;      // o*4 + ihalf
    const int o  = z >> 2;
    const int ihalf = z & 3;

    const int a = o ? 0 : 1;        // attn used: o1<-attn2, o2<-attn1
    const unsigned short* qb = (const unsigned short*)(ws + (a ? WS_QB2 : WS_QB1));
    const unsigned short* kb = (const unsigned short*)(ws + (a ? WS_KB2 : WS_KB1));
    const unsigned short* v  = (const unsigned short*)(ws + (o ? WS_V2 : WS_V1));
    const float  scale = o ? beta[0] : gamma[0];

    __shared__ unsigned short vt[64][72];   // v[c][i]
    __shared__ unsigned short pt[64][72];   // P[j][i]

    const int j0   = jt * 64;
    const int lane = t & 63;
    const int w    = t >> 6;
    const int n    = lane & 31;
    const int h    = lane >> 5;
    const int jh   = w & 1;
    const int ihq  = w >> 1;
    const int cbase = 32 * (w & 1);
    const int jbase = 32 * (w >> 1);

    const short8 kfrag = *(const short8*)(kb + (size_t)(b * NPX + j0 + 32 * jh + n) * 16 + h * 8);

    // staging indices (2 x 16B segments per thread)
    const int c0 = t >> 3, s80 = (t & 7) * 8;
    const int c1 = (t + 256) >> 3, s81 = ((t + 256) & 7) * 8;

    const int ibase = ihalf * 576;
    const unsigned short* vp0 = v + ((size_t)b * CCH + c0) * NPX + ibase + s80;
    const unsigned short* vp1 = v + ((size_t)b * CCH + c1) * NPX + ibase + s81;
    const unsigned short* qp  = qb + (size_t)(b * NPX + ibase + 32 * ihq + n) * 16 + h * 8;

    // prefetch chunk 0
    float4 vpre0 = *(const float4*)vp0;
    float4 vpre1 = *(const float4*)vp1;
    short8 qpre  = *(const short8*)qp;

    float16t oacc = {};

    for (int it = 0; it < 9; it++) {
        // issue next chunk's loads before the barriers
        vp0 += 64; vp1 += 64; qp += 64 * 16;
        float4 vn0 = vpre0, vn1 = vpre1;
        short8 qn = qpre;
        if (it + 1 < 9) {
            vn0 = *(const float4*)vp0;
            vn1 = *(const float4*)vp1;
            qn  = *(const short8*)qp;
        }

        __syncthreads();            // prior PV reads of vt/pt complete

        *(float4*)&vt[c0][s80] = vpre0;
        *(float4*)&vt[c1][s81] = vpre1;

        float16t sc = {};
        sc = __builtin_amdgcn_mfma_f32_32x32x16_bf16(qpre, kfrag, sc, 0, 0, 0);

        #pragma unroll
        for (int gq = 0; gq < 4; gq++) {
            const int ibl = 32 * ihq + 8 * gq + 4 * h;
            uint2 pk;
            pk.x = pack_bf16(fexp2(sc[gq * 4 + 0]), fexp2(sc[gq * 4 + 1]));
            pk.y = pack_bf16(fexp2(sc[gq * 4 + 2]), fexp2(sc[gq * 4 + 3]));
            *(uint2*)&pt[32 * jh + n][ibl] = pk;
        }
        __syncthreads();            // vt + pt ready

        #pragma unroll
        for (int kk = 0; kk < 4; kk++) {
            const short8 afrag = *(const short8*)&vt[cbase + n][kk * 16 + h * 8];
            const short8 bfrag = *(const short8*)&pt[jbase + n][kk * 16 + h * 8];
            oacc = __builtin_amdgcn_mfma_f32_32x32x16_bf16(afrag, bfrag, oacc, 0, 0, 0);
        }

        vpre0 = vn0; vpre1 = vn1; qpre = qn;
    }

    // epilogue: out += scale*acc (residual already in out). 32-bit indexing.
    float* outp = out + (o ? BCN : 0) + (b * CCH + cbase) * NPX + j0 + jbase + n;
    #pragma unroll
    for (int r = 0; r < 16; r++) {
        const int row = (r & 3) + 8 * (r >> 2) + 4 * h;
        atomicAdd(outp + row * NPX, oacc[r] * scale);
    }
}

// ---------------------------------------------------------------------------
extern "C" void kernel_launch(void* const* d_in, const int* in_sizes, int n_in,
                              void* d_out, int out_size, void* d_ws, size_t ws_size,
                              hipStream_t stream)
{
    const float* x1   = (const float*)d_in[0];
    const float* x2   = (const float*)d_in[1];
    const float* Wqk1 = (const float*)d_in[2];
    const float* bqk1 = (const float*)d_in[3];
    const float* Wqk2 = (const float*)d_in[4];
    const float* bqk2 = (const float*)d_in[5];
    const float* Wv1  = (const float*)d_in[6];
    const float* bv1  = (const float*)d_in[7];
    const float* Wv2  = (const float*)d_in[8];
    const float* bv2  = (const float*)d_in[9];
    const float* gamma = (const float*)d_in[10];
    const float* beta  = (const float*)d_in[11];
    float* out = (float*)d_out;
    float* ws  = (float*)d_ws;

    proj_kernel<<<dim3(72, 8), 256, 0, stream>>>(
        x1, x2, Wqk1, bqk1, Wqk2, bqk2, Wv1, bv1, Wv2, bv2, ws, out);
    stats_kernel<<<dim3(18, 8, 16), 256, 0, stream>>>(ws);
    merge_fold<<<dim3(36, 16), 256, 0, stream>>>(ws);
    out_kernel<<<dim3(36, 8, 8), 256, 0, stream>>>(gamma, beta, ws, out);
}